// Round 1
// baseline (137.577 us; speedup 1.0000x reference)
//
#include <hip/hip_runtime.h>
#include <math.h>

// Problem constants (match reference)
#define BDIM 8
#define NDIM 4096
#define KNBR 16
#define CDIM 192
#define COUT 192
#define TWO_C 384
#define ROWS (BDIM * NDIM)   // 32768
#define BM 32                // nodes per block tile
#define HSTRIDE 388          // padded LDS row stride (floats): 388%32=4 -> spreads banks, keeps 16B align
#define BN_EPS 1e-5f

// ---------------------------------------------------------------------------
// Kernel A: fused gather + max-relative aggregation + Linear (no bias; bias
// cancels in BatchNorm) + per-block partial BN stats (sum, sumsq) via atomics.
// Block: 192 threads (3 waves). Grid: 1024 blocks (32 nodes each).
// XCD affinity: batch = blockIdx.x % 8 so each XCD's L2 holds one batch's
// x-slab (3.1 MB) for the gather.
// ---------------------------------------------------------------------------
__global__ __launch_bounds__(192, 2)
void mrconv_fused(const float* __restrict__ x,      // [B][N][C]
                  const float* __restrict__ W,      // [2C][COUT]
                  const int*   __restrict__ edge,   // [B][N][K]
                  float*       __restrict__ y,      // [ROWS][COUT] (ws)
                  float*       __restrict__ stats)  // [2*COUT] sum, sumsq (zeroed)
{
    __shared__ float lds[BM * HSTRIDE];  // h tile: 32 x 384 (+pad). Reused for stats after.
    __shared__ int   eidx[BM * KNBR];

    const int t     = threadIdx.x;
    const int bid   = blockIdx.x;
    const int batch = bid & 7;           // XCD-affine
    const int tile  = bid >> 3;          // 0..127
    const int row0  = tile * BM;         // node index within batch

    const float* xb = x + (size_t)batch * NDIM * CDIM;
    const int*   eb = edge + (size_t)batch * NDIM * KNBR + (size_t)row0 * KNBR;

    // Stage edge indices for the whole tile (512 ints), coalesced.
    for (int i = t; i < BM * KNBR; i += 192) eidx[i] = eb[i];
    __syncthreads();

    // Gather + max-rel: thread t owns channel t for each node in the tile.
    for (int ln = 0; ln < BM; ++ln) {
        const int node = row0 + ln;
        const float xi = xb[(size_t)node * CDIM + t];
        float agg = -INFINITY;
#pragma unroll
        for (int k = 0; k < KNBR; ++k) {
            const int j = eidx[ln * KNBR + k];
            const float xj = xb[(size_t)j * CDIM + t];
            agg = fmaxf(agg, xj - xi);
        }
        lds[ln * HSTRIDE + t]        = xi;   // h[:, 0:192]  = x
        lds[ln * HSTRIDE + CDIM + t] = agg;  // h[:, 192:384] = agg
    }
    __syncthreads();

    // GEMM: y_tile[32][192] = h[32][384] @ W[384][192]
    // Thread (rg, cg): rows rg*4..+3, cols cg*8..+7. 192 = 8 rgroups * 24 cgroups.
    const int rg = t / 24;
    const int cg = t % 24;
    const int c0 = cg * 8;

    float acc[4][8];
#pragma unroll
    for (int a = 0; a < 4; ++a)
#pragma unroll
        for (int q = 0; q < 8; ++q) acc[a][q] = 0.0f;

    for (int j = 0; j < TWO_C; j += 4) {
        float4 hv[4];
#pragma unroll
        for (int ri = 0; ri < 4; ++ri)
            hv[ri] = *(const float4*)&lds[(rg * 4 + ri) * HSTRIDE + j];
#pragma unroll
        for (int jj = 0; jj < 4; ++jj) {
            const float4 wA = *(const float4*)&W[(j + jj) * COUT + c0];
            const float4 wB = *(const float4*)&W[(j + jj) * COUT + c0 + 4];
#pragma unroll
            for (int ri = 0; ri < 4; ++ri) {
                const float h = ((const float*)&hv[ri])[jj];
                acc[ri][0] = fmaf(h, wA.x, acc[ri][0]);
                acc[ri][1] = fmaf(h, wA.y, acc[ri][1]);
                acc[ri][2] = fmaf(h, wA.z, acc[ri][2]);
                acc[ri][3] = fmaf(h, wA.w, acc[ri][3]);
                acc[ri][4] = fmaf(h, wB.x, acc[ri][4]);
                acc[ri][5] = fmaf(h, wB.y, acc[ri][5]);
                acc[ri][6] = fmaf(h, wB.z, acc[ri][6]);
                acc[ri][7] = fmaf(h, wB.w, acc[ri][7]);
            }
        }
    }

    // Write y (pre-BN, no bias) coalesced as float4.
    const size_t grow0 = (size_t)batch * NDIM + row0;
#pragma unroll
    for (int ri = 0; ri < 4; ++ri) {
        const size_t r = grow0 + rg * 4 + ri;
        float4 o0 = {acc[ri][0], acc[ri][1], acc[ri][2], acc[ri][3]};
        float4 o1 = {acc[ri][4], acc[ri][5], acc[ri][6], acc[ri][7]};
        *(float4*)&y[r * COUT + c0]     = o0;
        *(float4*)&y[r * COUT + c0 + 4] = o1;
    }

    // Partial BN stats: per-thread sum over its 4 rows, reduce across rgroups
    // in LDS (reusing the h tile region), one atomicAdd per channel per block.
    __syncthreads();  // done with h tile
    float* psum = lds;              // [8][192]
    float* psq  = lds + 8 * COUT;   // [8][192]
#pragma unroll
    for (int ci = 0; ci < 8; ++ci) {
        float s = 0.0f, q = 0.0f;
#pragma unroll
        for (int ri = 0; ri < 4; ++ri) {
            const float v = acc[ri][ci];
            s += v;
            q += v * v;
        }
        psum[rg * COUT + c0 + ci] = s;
        psq [rg * COUT + c0 + ci] = q;
    }
    __syncthreads();
    if (t < COUT) {
        float s = 0.0f, q = 0.0f;
#pragma unroll
        for (int g = 0; g < 8; ++g) {
            s += psum[g * COUT + t];
            q += psq [g * COUT + t];
        }
        atomicAdd(&stats[t], s);
        atomicAdd(&stats[COUT + t], q);
    }
}

// ---------------------------------------------------------------------------
// Kernel C: BN-apply + exact GELU. Each block derives scale/shift from the
// global stats (cheap, L2-cached), then grid-strides over float4s.
// ---------------------------------------------------------------------------
__device__ __forceinline__ float gelu_exact(float v) {
    return 0.5f * v * (1.0f + erff(v * 0.70710678118654752440f));
}

__global__ __launch_bounds__(256)
void bn_gelu(const float* __restrict__ y,
             const float* __restrict__ stats,
             const float* __restrict__ gamma,
             const float* __restrict__ beta,
             float* __restrict__ out)
{
    __shared__ float sscale[COUT];
    __shared__ float sshift[COUT];
    const int t = threadIdx.x;
    if (t < COUT) {
        const float inv  = 1.0f / (float)ROWS;
        const float mean = stats[t] * inv;
        const float var  = stats[COUT + t] * inv - mean * mean;
        const float rstd = rsqrtf(var + BN_EPS);
        const float sc   = rstd * gamma[t];
        sscale[t] = sc;
        sshift[t] = beta[t] - mean * sc;
    }
    __syncthreads();

    const int total4 = ROWS * COUT / 4;          // 1,572,864 float4s
    const int stride = gridDim.x * blockDim.x;
    for (int i = blockIdx.x * blockDim.x + t; i < total4; i += stride) {
        const float4 v = ((const float4*)y)[i];
        const int c0 = (i % 48) * 4;             // 192/4 = 48 float4s per row
        float4 o;
        o.x = gelu_exact(fmaf(v.x, sscale[c0 + 0], sshift[c0 + 0]));
        o.y = gelu_exact(fmaf(v.y, sscale[c0 + 1], sshift[c0 + 1]));
        o.z = gelu_exact(fmaf(v.z, sscale[c0 + 2], sshift[c0 + 2]));
        o.w = gelu_exact(fmaf(v.w, sscale[c0 + 3], sshift[c0 + 3]));
        ((float4*)out)[i] = o;
    }
}

// ---------------------------------------------------------------------------
extern "C" void kernel_launch(void* const* d_in, const int* in_sizes, int n_in,
                              void* d_out, int out_size, void* d_ws, size_t ws_size,
                              hipStream_t stream) {
    const float* x     = (const float*)d_in[0];
    const float* W     = (const float*)d_in[1];
    // d_in[2] (bias) is intentionally unused: BatchNorm's mean-subtraction
    // cancels any per-channel bias added before it.
    const float* gamma = (const float*)d_in[3];
    const float* beta  = (const float*)d_in[4];
    const int*   edge  = (const int*)d_in[5];
    float* out = (float*)d_out;

    float* y     = (float*)d_ws;                       // [ROWS][COUT] = 25.17 MB
    float* stats = y + (size_t)ROWS * COUT;            // [2*COUT]

    hipMemsetAsync(stats, 0, 2 * COUT * sizeof(float), stream);
    mrconv_fused<<<dim3(ROWS / BM), dim3(192), 0, stream>>>(x, W, edge, y, stats);
    bn_gelu<<<dim3(2048), dim3(256), 0, stream>>>(y, stats, gamma, beta, out);
}

// Round 2
// 59.909 us; speedup vs baseline: 2.2964x; 2.2964x over previous
//
#include <hip/hip_runtime.h>
#include <math.h>

// Problem constants
#define BDIM 8
#define NDIM 4096
#define KNBR 16
#define CDIM 192
#define COUT 192
#define TWO_C 384
#define ROWS (BDIM * NDIM)   // 32768
#define BN_EPS 1e-5f

#define BM 64                 // nodes per block
#define HS 392                // h LDS row stride in bf16 elems (784 B: 16B-aligned, 2-way banks)
#define KSTEPS 12             // 384 / 32
#define NTILES 12             // 192 / 16

typedef __attribute__((ext_vector_type(8))) short short8;
typedef __attribute__((ext_vector_type(4))) float f32x4;

__device__ __forceinline__ float bf2f(unsigned short u) {
    unsigned int x = ((unsigned int)u) << 16;
    return __builtin_bit_cast(float, x);
}
__device__ __forceinline__ unsigned short f2bf(float f) {
    unsigned int u = __builtin_bit_cast(unsigned int, f);
    u += 0x7FFFu + ((u >> 16) & 1u);   // RNE
    return (unsigned short)(u >> 16);
}
__device__ __forceinline__ float gelu_exact(float v) {
    return 0.5f * v * (1.0f + erff(v * 0.70710678118654752440f));
}

// ---------------------------------------------------------------------------
// Pre-kernel 1: x fp32 -> bf16 (halves gather traffic). 8 elems/thread.
// ---------------------------------------------------------------------------
__global__ __launch_bounds__(256)
void cvt_x(const float* __restrict__ x, unsigned short* __restrict__ xb, int n8) {
    int i = blockIdx.x * 256 + threadIdx.x;
    if (i >= n8) return;
    const float4* p = (const float4*)(x + (size_t)i * 8);
    float4 a = p[0], b = p[1];
    short8 o;
    o[0] = (short)f2bf(a.x); o[1] = (short)f2bf(a.y);
    o[2] = (short)f2bf(a.z); o[3] = (short)f2bf(a.w);
    o[4] = (short)f2bf(b.x); o[5] = (short)f2bf(b.y);
    o[6] = (short)f2bf(b.z); o[7] = (short)f2bf(b.w);
    *(short8*)(xb + (size_t)i * 8) = o;
}

// ---------------------------------------------------------------------------
// Pre-kernel 2: pack W [384][192] fp32 -> fragment-ordered bf16.
// Wtp[((ks*12 + nt)*64 + lane)*8 + j] = bf16(W[ks*32 + (lane>>4)*8 + j][nt*16 + (lane&15)])
// so a B-fragment load is one coalesced dwordx4 per lane.
// ---------------------------------------------------------------------------
__global__ __launch_bounds__(256)
void pack_w(const float* __restrict__ W, unsigned short* __restrict__ Wtp) {
    int tid = blockIdx.x * 256 + threadIdx.x;   // < 12*12*64 = 9216
    if (tid >= KSTEPS * NTILES * 64) return;
    int ks = tid / (NTILES * 64);
    int r  = tid % (NTILES * 64);
    int nt = r / 64;
    int l  = r % 64;
    int k0 = ks * 32 + ((l >> 4) << 3);
    int c  = nt * 16 + (l & 15);
    short8 o;
#pragma unroll
    for (int j = 0; j < 8; ++j)
        o[j] = (short)f2bf(W[(size_t)(k0 + j) * COUT + c]);
    *(short8*)(Wtp + (size_t)tid * 8) = o;
}

// ---------------------------------------------------------------------------
// Main fused kernel: gather + max-rel -> h (bf16, LDS) -> MFMA GEMM -> y bf16
// + per-channel BN partial stats. 192 threads (3 waves), 64 nodes/block.
// batch = bid & 7 -> XCD-affine gather (1.6 MB bf16 slab per XCD L2).
// ---------------------------------------------------------------------------
__global__ __launch_bounds__(192)
void mrconv_mfma(const unsigned short* __restrict__ xb,   // [B][N][C] bf16
                 const unsigned short* __restrict__ Wtp,  // fragment-packed bf16
                 const int*   __restrict__ edge,          // [B][N][K]
                 unsigned short* __restrict__ y,          // [ROWS][COUT] bf16
                 float* __restrict__ stats)               // [2*COUT] zeroed
{
    __shared__ unsigned short h[BM * HS];   // 50176 B
    __shared__ int eidx[BM * KNBR];         // 4096 B

    const int t     = threadIdx.x;
    const int bid   = blockIdx.x;
    const int batch = bid & 7;
    const int tile  = bid >> 3;
    const int row0  = tile * BM;

    const unsigned short* xbb = xb + (size_t)batch * NDIM * CDIM;
    const int* eb = edge + ((size_t)batch * NDIM + row0) * KNBR;

    for (int i = t; i < BM * KNBR; i += 192) eidx[i] = eb[i];
    __syncthreads();

    // ---- gather + max-relative, 8 channels/thread, 8 nodes per iteration ----
    {
        const int cc = t % 24;        // channel chunk: channels cc*8 .. cc*8+7
        const int sn = t / 24;        // 0..7
        for (int it = 0; it < 8; ++it) {
            const int ln = it * 8 + sn;
            const unsigned short* xr = xbb + (size_t)(row0 + ln) * CDIM + cc * 8;
            short8 xi8 = *(const short8*)xr;
            float xif[8], agg[8];
#pragma unroll
            for (int q = 0; q < 8; ++q) {
                xif[q] = bf2f((unsigned short)xi8[q]);
                agg[q] = -INFINITY;
            }
#pragma unroll
            for (int k = 0; k < KNBR; ++k) {
                const int j = eidx[ln * KNBR + k];
                short8 xj8 = *(const short8*)(xbb + (size_t)j * CDIM + cc * 8);
#pragma unroll
                for (int q = 0; q < 8; ++q)
                    agg[q] = fmaxf(agg[q], bf2f((unsigned short)xj8[q]) - xif[q]);
            }
            *(short8*)&h[ln * HS + cc * 8] = xi8;          // h[:,0:192] = x
            short8 a8;
#pragma unroll
            for (int q = 0; q < 8; ++q) a8[q] = (short)f2bf(agg[q]);
            *(short8*)&h[ln * HS + CDIM + cc * 8] = a8;    // h[:,192:384] = agg
        }
    }
    __syncthreads();

    // ---- MFMA GEMM: y_tile[64][192] = h[64][384] @ W[384][192] ----
    // wave wv owns cols wv*64 .. +63 (4 ntiles), all 64 rows (4 mtiles).
    const int wv   = t >> 6;
    const int lane = t & 63;
    const int lrow = lane & 15;
    const int lk   = (lane >> 4) << 3;

    f32x4 acc[4][4];
#pragma unroll
    for (int mt = 0; mt < 4; ++mt)
#pragma unroll
        for (int nt = 0; nt < 4; ++nt)
            acc[mt][nt] = (f32x4){0.f, 0.f, 0.f, 0.f};

    for (int ks = 0; ks < KSTEPS; ++ks) {
        short8 bfr[4], afr[4];
#pragma unroll
        for (int nt = 0; nt < 4; ++nt) {
            const int ng = wv * 4 + nt;
            bfr[nt] = *(const short8*)(Wtp + (size_t)((ks * NTILES + ng) * 64 + lane) * 8);
        }
#pragma unroll
        for (int mt = 0; mt < 4; ++mt)
            afr[mt] = *(const short8*)&h[(mt * 16 + lrow) * HS + ks * 32 + lk];
#pragma unroll
        for (int mt = 0; mt < 4; ++mt)
#pragma unroll
            for (int nt = 0; nt < 4; ++nt)
                acc[mt][nt] = __builtin_amdgcn_mfma_f32_16x16x32_bf16(
                    afr[mt], bfr[nt], acc[mt][nt], 0, 0, 0);
    }

    // ---- write y (bf16) + BN partial stats ----
    const size_t growbase = (size_t)batch * NDIM + row0;
    const int rj = (lane >> 4) << 2;   // C/D: row = (lane>>4)*4 + j
#pragma unroll
    for (int mt = 0; mt < 4; ++mt) {
#pragma unroll
        for (int nt = 0; nt < 4; ++nt) {
            const int col = wv * 64 + nt * 16 + lrow;   // C/D: col = lane&15
#pragma unroll
            for (int j = 0; j < 4; ++j) {
                const size_t rr = growbase + mt * 16 + rj + j;
                y[rr * COUT + col] = f2bf(acc[mt][nt][j]);
            }
        }
    }

#pragma unroll
    for (int nt = 0; nt < 4; ++nt) {
        float s = 0.f, q = 0.f;
#pragma unroll
        for (int mt = 0; mt < 4; ++mt)
#pragma unroll
            for (int j = 0; j < 4; ++j) {
                const float v = acc[mt][nt][j];
                s += v; q += v * v;
            }
        s += __shfl_xor(s, 16); s += __shfl_xor(s, 32);
        q += __shfl_xor(q, 16); q += __shfl_xor(q, 32);
        if (lane < 16) {
            const int col = wv * 64 + nt * 16 + lane;
            atomicAdd(&stats[col], s);
            atomicAdd(&stats[COUT + col], q);
        }
    }
}

// ---------------------------------------------------------------------------
// BN-apply + exact GELU: bf16 y -> fp32 out. 8 elems/thread, exact grid.
// ---------------------------------------------------------------------------
__global__ __launch_bounds__(256)
void bn_gelu(const unsigned short* __restrict__ y,
             const float* __restrict__ stats,
             const float* __restrict__ gamma,
             const float* __restrict__ beta,
             float* __restrict__ out)
{
    __shared__ float sscale[COUT];
    __shared__ float sshift[COUT];
    const int t = threadIdx.x;
    if (t < COUT) {
        const float inv  = 1.0f / (float)ROWS;
        const float mean = stats[t] * inv;
        const float var  = stats[COUT + t] * inv - mean * mean;
        const float rstd = rsqrtf(var + BN_EPS);
        const float sc   = rstd * gamma[t];
        sscale[t] = sc;
        sshift[t] = beta[t] - mean * sc;
    }
    __syncthreads();

    const int i = blockIdx.x * 256 + t;          // grid sized exactly: 786432
    if (i >= ROWS * COUT / 8) return;
    short8 v = *(const short8*)(y + (size_t)i * 8);
    const int c0 = (i % 24) * 8;
    float4 o0, o1;
    o0.x = gelu_exact(fmaf(bf2f((unsigned short)v[0]), sscale[c0 + 0], sshift[c0 + 0]));
    o0.y = gelu_exact(fmaf(bf2f((unsigned short)v[1]), sscale[c0 + 1], sshift[c0 + 1]));
    o0.z = gelu_exact(fmaf(bf2f((unsigned short)v[2]), sscale[c0 + 2], sshift[c0 + 2]));
    o0.w = gelu_exact(fmaf(bf2f((unsigned short)v[3]), sscale[c0 + 3], sshift[c0 + 3]));
    o1.x = gelu_exact(fmaf(bf2f((unsigned short)v[4]), sscale[c0 + 4], sshift[c0 + 4]));
    o1.y = gelu_exact(fmaf(bf2f((unsigned short)v[5]), sscale[c0 + 5], sshift[c0 + 5]));
    o1.z = gelu_exact(fmaf(bf2f((unsigned short)v[6]), sscale[c0 + 6], sshift[c0 + 6]));
    o1.w = gelu_exact(fmaf(bf2f((unsigned short)v[7]), sscale[c0 + 7], sshift[c0 + 7]));
    float4* po = (float4*)(out + (size_t)i * 8);
    po[0] = o0;
    po[1] = o1;
}

// ---------------------------------------------------------------------------
extern "C" void kernel_launch(void* const* d_in, const int* in_sizes, int n_in,
                              void* d_out, int out_size, void* d_ws, size_t ws_size,
                              hipStream_t stream) {
    const float* x     = (const float*)d_in[0];
    const float* W     = (const float*)d_in[1];
    // d_in[2] (bias) unused: BatchNorm mean-subtraction cancels it exactly.
    const float* gamma = (const float*)d_in[3];
    const float* beta  = (const float*)d_in[4];
    const int*   edge  = (const int*)d_in[5];
    float* out = (float*)d_out;

    unsigned short* xb16 = (unsigned short*)d_ws;                  // 12.58 MB
    unsigned short* y16  = xb16 + (size_t)ROWS * CDIM;             // 12.58 MB
    unsigned short* Wtp  = y16 + (size_t)ROWS * COUT;              // 147456 B
    float* stats = (float*)(Wtp + (size_t)KSTEPS * NTILES * 64 * 8); // 1536 B

    hipMemsetAsync(stats, 0, 2 * COUT * sizeof(float), stream);
    cvt_x <<<dim3((ROWS * CDIM / 8 + 255) / 256), dim3(256), 0, stream>>>(x, xb16, ROWS * CDIM / 8);
    pack_w<<<dim3(36), dim3(256), 0, stream>>>(W, Wtp);
    mrconv_mfma<<<dim3(ROWS / BM), dim3(192), 0, stream>>>(xb16, Wtp, edge, y16, stats);
    bn_gelu<<<dim3(ROWS * COUT / 8 / 256), dim3(256), 0, stream>>>(y16, stats, gamma, beta, out);
}

// Round 3
// 54.560 us; speedup vs baseline: 2.5216x; 1.0980x over previous
//
#include <hip/hip_runtime.h>
#include <math.h>

// Problem constants
#define BDIM 8
#define NDIM 4096
#define KNBR 16
#define CDIM 192
#define COUT 192
#define TWO_C 384
#define ROWS (BDIM * NDIM)   // 32768
#define BN_EPS 1e-5f

#define BM 64                 // nodes per block
#define HS 392                // h LDS row stride in bf16 elems (784 B: 16B-aligned, 2-way banks)
#define KSTEPS 12             // 384 / 32
#define NTILES 12             // 192 / 16

typedef __attribute__((ext_vector_type(8))) short short8;
typedef __attribute__((ext_vector_type(4))) float f32x4;

__device__ __forceinline__ float bf2f(unsigned short u) {
    unsigned int x = ((unsigned int)u) << 16;
    return __builtin_bit_cast(float, x);
}
__device__ __forceinline__ unsigned short f2bf(float f) {
    unsigned int u = __builtin_bit_cast(unsigned int, f);
    u += 0x7FFFu + ((u >> 16) & 1u);   // RNE
    return (unsigned short)(u >> 16);
}
__device__ __forceinline__ float gelu_exact(float v) {
    return 0.5f * v * (1.0f + erff(v * 0.70710678118654752440f));
}

// ---------------------------------------------------------------------------
// Pre-kernel 1: x fp32 -> bf16 (halves gather traffic). 8 elems/thread.
// Block 0 also zeroes the BN stats accumulator (replaces the pathological
// ~40 us tiny hipMemsetAsync graph node seen in round-2 rocprof).
// ---------------------------------------------------------------------------
__global__ __launch_bounds__(256)
void cvt_x(const float* __restrict__ x, unsigned short* __restrict__ xb, int n8,
           float* __restrict__ stats) {
    if (blockIdx.x == 0) {
        for (int s = threadIdx.x; s < 2 * COUT; s += 256) stats[s] = 0.0f;
    }
    int i = blockIdx.x * 256 + threadIdx.x;
    if (i >= n8) return;
    const float4* p = (const float4*)(x + (size_t)i * 8);
    float4 a = p[0], b = p[1];
    short8 o;
    o[0] = (short)f2bf(a.x); o[1] = (short)f2bf(a.y);
    o[2] = (short)f2bf(a.z); o[3] = (short)f2bf(a.w);
    o[4] = (short)f2bf(b.x); o[5] = (short)f2bf(b.y);
    o[6] = (short)f2bf(b.z); o[7] = (short)f2bf(b.w);
    *(short8*)(xb + (size_t)i * 8) = o;
}

// ---------------------------------------------------------------------------
// Pre-kernel 2: pack W [384][192] fp32 -> fragment-ordered bf16.
// Wtp[((ks*12 + nt)*64 + lane)*8 + j] = bf16(W[ks*32 + (lane>>4)*8 + j][nt*16 + (lane&15)])
// so a B-fragment load is one coalesced dwordx4 per lane.
// ---------------------------------------------------------------------------
__global__ __launch_bounds__(256)
void pack_w(const float* __restrict__ W, unsigned short* __restrict__ Wtp) {
    int tid = blockIdx.x * 256 + threadIdx.x;   // < 12*12*64 = 9216
    if (tid >= KSTEPS * NTILES * 64) return;
    int ks = tid / (NTILES * 64);
    int r  = tid % (NTILES * 64);
    int nt = r / 64;
    int l  = r % 64;
    int k0 = ks * 32 + ((l >> 4) << 3);
    int c  = nt * 16 + (l & 15);
    short8 o;
#pragma unroll
    for (int j = 0; j < 8; ++j)
        o[j] = (short)f2bf(W[(size_t)(k0 + j) * COUT + c]);
    *(short8*)(Wtp + (size_t)tid * 8) = o;
}

// ---------------------------------------------------------------------------
// Main fused kernel: gather + max-rel -> h (bf16, LDS) -> MFMA GEMM -> y bf16
// + per-channel BN partial stats. 192 threads (3 waves), 64 nodes/block.
// batch = bid & 7 -> XCD-affine gather (1.6 MB bf16 slab per XCD L2).
// ---------------------------------------------------------------------------
__global__ __launch_bounds__(192)
void mrconv_mfma(const unsigned short* __restrict__ xb,   // [B][N][C] bf16
                 const unsigned short* __restrict__ Wtp,  // fragment-packed bf16
                 const int*   __restrict__ edge,          // [B][N][K]
                 unsigned short* __restrict__ y,          // [ROWS][COUT] bf16
                 float* __restrict__ stats)               // [2*COUT] zeroed
{
    __shared__ unsigned short h[BM * HS];   // 50176 B
    __shared__ int eidx[BM * KNBR];         // 4096 B

    const int t     = threadIdx.x;
    const int bid   = blockIdx.x;
    const int batch = bid & 7;
    const int tile  = bid >> 3;
    const int row0  = tile * BM;

    const unsigned short* xbb = xb + (size_t)batch * NDIM * CDIM;
    const int* eb = edge + ((size_t)batch * NDIM + row0) * KNBR;

    for (int i = t; i < BM * KNBR; i += 192) eidx[i] = eb[i];
    __syncthreads();

    // ---- gather + max-relative, 8 channels/thread, 8 nodes per iteration ----
    {
        const int cc = t % 24;        // channel chunk: channels cc*8 .. cc*8+7
        const int sn = t / 24;        // 0..7
        for (int it = 0; it < 8; ++it) {
            const int ln = it * 8 + sn;
            const unsigned short* xr = xbb + (size_t)(row0 + ln) * CDIM + cc * 8;
            short8 xi8 = *(const short8*)xr;
            float xif[8], agg[8];
#pragma unroll
            for (int q = 0; q < 8; ++q) {
                xif[q] = bf2f((unsigned short)xi8[q]);
                agg[q] = -INFINITY;
            }
#pragma unroll
            for (int k = 0; k < KNBR; ++k) {
                const int j = eidx[ln * KNBR + k];
                short8 xj8 = *(const short8*)(xbb + (size_t)j * CDIM + cc * 8);
#pragma unroll
                for (int q = 0; q < 8; ++q)
                    agg[q] = fmaxf(agg[q], bf2f((unsigned short)xj8[q]) - xif[q]);
            }
            *(short8*)&h[ln * HS + cc * 8] = xi8;          // h[:,0:192] = x
            short8 a8;
#pragma unroll
            for (int q = 0; q < 8; ++q) a8[q] = (short)f2bf(agg[q]);
            *(short8*)&h[ln * HS + CDIM + cc * 8] = a8;    // h[:,192:384] = agg
        }
    }
    __syncthreads();

    // ---- MFMA GEMM: y_tile[64][192] = h[64][384] @ W[384][192] ----
    // wave wv owns cols wv*64 .. +63 (4 ntiles), all 64 rows (4 mtiles).
    const int wv   = t >> 6;
    const int lane = t & 63;
    const int lrow = lane & 15;
    const int lk   = (lane >> 4) << 3;

    f32x4 acc[4][4];
#pragma unroll
    for (int mt = 0; mt < 4; ++mt)
#pragma unroll
        for (int nt = 0; nt < 4; ++nt)
            acc[mt][nt] = (f32x4){0.f, 0.f, 0.f, 0.f};

    for (int ks = 0; ks < KSTEPS; ++ks) {
        short8 bfr[4], afr[4];
#pragma unroll
        for (int nt = 0; nt < 4; ++nt) {
            const int ng = wv * 4 + nt;
            bfr[nt] = *(const short8*)(Wtp + (size_t)((ks * NTILES + ng) * 64 + lane) * 8);
        }
#pragma unroll
        for (int mt = 0; mt < 4; ++mt)
            afr[mt] = *(const short8*)&h[(mt * 16 + lrow) * HS + ks * 32 + lk];
#pragma unroll
        for (int mt = 0; mt < 4; ++mt)
#pragma unroll
            for (int nt = 0; nt < 4; ++nt)
                acc[mt][nt] = __builtin_amdgcn_mfma_f32_16x16x32_bf16(
                    afr[mt], bfr[nt], acc[mt][nt], 0, 0, 0);
    }

    // ---- write y (bf16) + BN partial stats ----
    const size_t growbase = (size_t)batch * NDIM + row0;
    const int rj = (lane >> 4) << 2;   // C/D: row = (lane>>4)*4 + j
#pragma unroll
    for (int mt = 0; mt < 4; ++mt) {
#pragma unroll
        for (int nt = 0; nt < 4; ++nt) {
            const int col = wv * 64 + nt * 16 + lrow;   // C/D: col = lane&15
#pragma unroll
            for (int j = 0; j < 4; ++j) {
                const size_t rr = growbase + mt * 16 + rj + j;
                y[rr * COUT + col] = f2bf(acc[mt][nt][j]);
            }
        }
    }

#pragma unroll
    for (int nt = 0; nt < 4; ++nt) {
        float s = 0.f, q = 0.f;
#pragma unroll
        for (int mt = 0; mt < 4; ++mt)
#pragma unroll
            for (int j = 0; j < 4; ++j) {
                const float v = acc[mt][nt][j];
                s += v; q += v * v;
            }
        s += __shfl_xor(s, 16); s += __shfl_xor(s, 32);
        q += __shfl_xor(q, 16); q += __shfl_xor(q, 32);
        if (lane < 16) {
            const int col = wv * 64 + nt * 16 + lane;
            atomicAdd(&stats[col], s);
            atomicAdd(&stats[COUT + col], q);
        }
    }
}

// ---------------------------------------------------------------------------
// BN-apply + exact GELU: bf16 y -> fp32 out. 8 elems/thread, exact grid.
// ---------------------------------------------------------------------------
__global__ __launch_bounds__(256)
void bn_gelu(const unsigned short* __restrict__ y,
             const float* __restrict__ stats,
             const float* __restrict__ gamma,
             const float* __restrict__ beta,
             float* __restrict__ out)
{
    __shared__ float sscale[COUT];
    __shared__ float sshift[COUT];
    const int t = threadIdx.x;
    if (t < COUT) {
        const float inv  = 1.0f / (float)ROWS;
        const float mean = stats[t] * inv;
        const float var  = stats[COUT + t] * inv - mean * mean;
        const float rstd = rsqrtf(var + BN_EPS);
        const float sc   = rstd * gamma[t];
        sscale[t] = sc;
        sshift[t] = beta[t] - mean * sc;
    }
    __syncthreads();

    const int i = blockIdx.x * 256 + t;          // grid sized exactly: 786432
    if (i >= ROWS * COUT / 8) return;
    short8 v = *(const short8*)(y + (size_t)i * 8);
    const int c0 = (i % 24) * 8;
    float4 o0, o1;
    o0.x = gelu_exact(fmaf(bf2f((unsigned short)v[0]), sscale[c0 + 0], sshift[c0 + 0]));
    o0.y = gelu_exact(fmaf(bf2f((unsigned short)v[1]), sscale[c0 + 1], sshift[c0 + 1]));
    o0.z = gelu_exact(fmaf(bf2f((unsigned short)v[2]), sscale[c0 + 2], sshift[c0 + 2]));
    o0.w = gelu_exact(fmaf(bf2f((unsigned short)v[3]), sscale[c0 + 3], sshift[c0 + 3]));
    o1.x = gelu_exact(fmaf(bf2f((unsigned short)v[4]), sscale[c0 + 4], sshift[c0 + 4]));
    o1.y = gelu_exact(fmaf(bf2f((unsigned short)v[5]), sscale[c0 + 5], sshift[c0 + 5]));
    o1.z = gelu_exact(fmaf(bf2f((unsigned short)v[6]), sscale[c0 + 6], sshift[c0 + 6]));
    o1.w = gelu_exact(fmaf(bf2f((unsigned short)v[7]), sscale[c0 + 7], sshift[c0 + 7]));
    float4* po = (float4*)(out + (size_t)i * 8);
    po[0] = o0;
    po[1] = o1;
}

// ---------------------------------------------------------------------------
extern "C" void kernel_launch(void* const* d_in, const int* in_sizes, int n_in,
                              void* d_out, int out_size, void* d_ws, size_t ws_size,
                              hipStream_t stream) {
    const float* x     = (const float*)d_in[0];
    const float* W     = (const float*)d_in[1];
    // d_in[2] (bias) unused: BatchNorm mean-subtraction cancels it exactly.
    const float* gamma = (const float*)d_in[3];
    const float* beta  = (const float*)d_in[4];
    const int*   edge  = (const int*)d_in[5];
    float* out = (float*)d_out;

    unsigned short* xb16 = (unsigned short*)d_ws;                  // 12.58 MB
    unsigned short* y16  = xb16 + (size_t)ROWS * CDIM;             // 12.58 MB
    unsigned short* Wtp  = y16 + (size_t)ROWS * COUT;              // 147456 B
    float* stats = (float*)(Wtp + (size_t)KSTEPS * NTILES * 64 * 8); // 1536 B

    // No hipMemsetAsync: a 1.5 KB fill node cost ~40 us in the replayed graph
    // (round-2 rocprof). cvt_x block 0 zeroes stats instead; stream order
    // guarantees it completes before mrconv_mfma's atomics.
    cvt_x <<<dim3((ROWS * CDIM / 8 + 255) / 256), dim3(256), 0, stream>>>(x, xb16, ROWS * CDIM / 8, stats);
    pack_w<<<dim3(36), dim3(256), 0, stream>>>(W, Wtp);
    mrconv_mfma<<<dim3(ROWS / BM), dim3(192), 0, stream>>>(xb16, Wtp, edge, y16, stats);
    bn_gelu<<<dim3(ROWS * COUT / 8 / 256), dim3(256), 0, stream>>>(y16, stats, gamma, beta, out);
}